// Round 2
// baseline (1158.231 us; speedup 1.0000x reference)
//
#include <hip/hip_runtime.h>
#include <hip/hip_bf16.h>

// DecoderRNN, fp32 in / fp32 out (reference dtypes), bf16 MFMA compute.
// Attention branch is dead code (softmax over a length-1 axis == 1 =>
// context == encoder_out; We/be/Wd/bd/Wf/bf never affect the output).
//   A) pre[t][g][b] = [emb(cap[b,t]), enc[b]] @ W_ih^T + b_ih + b_hh  (GEMM)
//      -> fp32, stored INSIDE d_out (dead space until out_kernel overwrites)
//   B) 64-step LSTM recurrence: 16 WGs x 128 gate rows, Whh in VGPRs.
//      IN-BAND publication: Hall is poison-memset (0xFF); writers publish h
//      via relaxed-agent u64 stores (write-through to LLC, no drain/flag/
//      fence); readers poll the operand words themselves (relaxed-agent u64
//      loads, batched rounds, per-slice __all -> MFMA on arrival).
//      240 spare WGs in the same dispatch convert Wfc -> bf16 (overlapped).
//   C) out = Hall @ W_fc^T + b_fc  (2048 x 30000 x 512), global_load_lds
//      staging of both bf16 operands.

#define BATCH 32
#define TT 64
#define VV 30000
#define HH 512
#define G4 2048     // 4*H
#define KX 768      // EMB + E
#define RNN_WG 16   // recurrence workgroups (128 gate rows each)

typedef __bf16 bf16x8 __attribute__((ext_vector_type(8)));
typedef float f32x4 __attribute__((ext_vector_type(4)));
typedef __attribute__((address_space(1))) void gvoid;
typedef __attribute__((address_space(3))) void lvoid;
typedef unsigned long long u64;

#define POISON 0xFFFFFFFFFFFFFFFFull   // 4x bf16 0xFFFF (-NaN): unreachable for h

#define MFMA(a, b, c) __builtin_amdgcn_mfma_f32_16x16x32_bf16((a), (b), (c), 0, 0, 0)

__device__ __forceinline__ float sigf(float x) {
    return 1.0f / (1.0f + __expf(-x));   // safe: x=+-inf -> 0/1
}
__device__ __forceinline__ float tanh_fast(float x) {
    return 1.0f - 2.0f / (__expf(2.0f * x) + 1.0f);   // safe at +-inf
}
__device__ __forceinline__ bf16x8 cvt8(const float* __restrict__ p) {
    const f32x4 a = *(const f32x4*)p;
    const f32x4 b = *(const f32x4*)(p + 4);
    bf16x8 r;
    r[0] = (__bf16)a[0]; r[1] = (__bf16)a[1]; r[2] = (__bf16)a[2]; r[3] = (__bf16)a[3];
    r[4] = (__bf16)b[0]; r[5] = (__bf16)b[1]; r[6] = (__bf16)b[2]; r[7] = (__bf16)b[3];
    return r;
}
__device__ __forceinline__ u64 aload(const __bf16* p) {
    return __hip_atomic_load((const u64*)p, __ATOMIC_RELAXED,
                             __HIP_MEMORY_SCOPE_AGENT);
}

// ---------------------------------------------------------------------------
// Kernel A: pre[t][g][b] fp32, layout [T][2048][32]. 128x128xK768 per WG.
// M index m = t*32 + b.  (unchanged)
// ---------------------------------------------------------------------------
__global__ __launch_bounds__(256) void pre_kernel(
    const float* __restrict__ enc, const int* __restrict__ captions,
    const float* __restrict__ emb, const float* __restrict__ Wih,
    const float* __restrict__ bih, const float* __restrict__ bhh,
    float* __restrict__ pre) {
    __shared__ __bf16 aT[128 * 32];
    __shared__ __bf16 bT[128 * 32];
    __shared__ int capm[128];

    const int tid = threadIdx.x;
    const int nt = blockIdx.x;   // gate tile [0,16)
    const int mt = blockIdx.y;   // token tile [0,16)

    if (tid < 128) {
        int m = mt * 128 + tid;               // m = t*32 + b
        capm[tid] = captions[(m & 31) * TT + (m >> 5)];
    }

    const int lane = tid & 63, wv = tid >> 6;
    const int ln = lane & 15, quad = lane >> 4;
    const int wm = wv & 1, wn = wv >> 1;

    f32x4 acc[4][4] = {};
    __syncthreads();

    for (int kc = 0; kc < 24; ++kc) {
        const int k0 = kc * 32;
        for (int i = tid; i < 512; i += 256) {
            int r = i >> 2, seg = i & 3;
            const float* src;
            if (k0 < 512) {
                src = emb + (size_t)capm[r] * 512 + k0 + seg * 8;
            } else {
                int b = (mt * 128 + r) & 31;
                src = enc + b * 256 + (k0 - 512) + seg * 8;
            }
            *(bf16x8*)&aT[r * 32 + seg * 8] = cvt8(src);
            *(bf16x8*)&bT[r * 32 + seg * 8] =
                cvt8(&Wih[(size_t)(nt * 128 + r) * KX + k0 + seg * 8]);
        }
        __syncthreads();
        bf16x8 af[4], bfr[4];
        for (int x = 0; x < 4; ++x) {
            af[x]  = *(const bf16x8*)&aT[(wm * 64 + x * 16 + ln) * 32 + quad * 8];
            bfr[x] = *(const bf16x8*)&bT[(wn * 64 + x * 16 + ln) * 32 + quad * 8];
        }
        for (int mi = 0; mi < 4; ++mi)
            for (int ni = 0; ni < 4; ++ni)
                acc[mi][ni] = MFMA(af[mi], bfr[ni], acc[mi][ni]);
        __syncthreads();
    }

    for (int ni = 0; ni < 4; ++ni) {
        int g = nt * 128 + wn * 64 + ni * 16 + ln;
        float bias = bih[g] + bhh[g];
        for (int mi = 0; mi < 4; ++mi) {
            int m = mt * 128 + wm * 64 + mi * 16 + quad * 4;  // m = t*32+b, b%4==0
            int t = m >> 5, b = m & 31;
            f32x4 v = acc[mi][ni];
            v[0] += bias; v[1] += bias; v[2] += bias; v[3] += bias;
            *(f32x4*)&pre[((size_t)t * G4 + g) * BATCH + b] = v;
        }
    }
}

// ---------------------------------------------------------------------------
// Kernel B: recurrence, in-band data publication.
// WG w owns h-cols [32w,32w+32) => 128 gate rows (gate-type q = wave index).
// Whh staged once through LDS then hoisted to bfrag[2][16] VGPRs; gst scratch
// aliases the staging buffer. Per step:
//   - acc init from register-prefetched pre[t]; prefetch pre[t+1]
//   - issue all 64 A-operand u64 loads (relaxed-agent, L1/L2-bypass)
//   - poll rounds: per K-slice, if __all(all 4 u64 != POISON) -> 4 MFMAs,
//     clear; reload only still-poisoned slices (one pipelined LLC trip/round)
//   - gst transpose (LDS), pointwise, publish h via relaxed-agent u64 stores
// No flags, no fences, no store drain on the publish path. Poison 0xFFFF is
// unreachable: h = sig(o)*tanh(c) is finite (|h|<=1) for all finite inputs.
// WGs [16,256): convert Wfc (fp32) -> bf16 (overlapped, independent).
// ---------------------------------------------------------------------------
__global__ __launch_bounds__(256, 1) void rnn_kernel(
    const float* __restrict__ pre, const float* __restrict__ Whh,
    __bf16* __restrict__ Hall,
    const float* __restrict__ Wfc, __bf16* __restrict__ Wfc16) {
    __shared__ char smem[131072];   // 128 KiB: whh staging, then gst scratch

    if (blockIdx.x >= RNN_WG) {
        // ---- Wfc -> bf16 conversion (grid-stride over 8-elem chunks) ----
        if (Wfc16) {
            const int stride = (gridDim.x - RNN_WG) * 256;
            int idx = (blockIdx.x - RNN_WG) * 256 + threadIdx.x;
            for (int i = idx; i < VV * HH / 8; i += stride)
                *(bf16x8*)&Wfc16[(size_t)i * 8] = cvt8(&Wfc[(size_t)i * 8]);
        }
        return;
    }

    __bf16* whh = (__bf16*)smem;    // [128][512] — dead after fragment hoist
    float*  gst = (float*)smem;     // [128][36]  — aliases whh afterwards

    const int tid = threadIdx.x;
    const int w = blockIdx.x;
    const int lane = tid & 63, wv = tid >> 6;
    const int ln = lane & 15, quad = lane >> 4;

    // stage Whh slice (row r: gate type r>>5, h-col w*32+(r&31)), fp32->bf16
    for (int i = tid; i < 128 * 64; i += 256) {
        int r = i >> 6, k = (i & 63) << 3;
        int g = (r >> 5) * 512 + w * 32 + (r & 31);
        *(bf16x8*)&whh[r * 512 + k] = cvt8(&Whh[(size_t)g * HH + k]);
    }
    __syncthreads();

    // hoist B fragments: wave wv = gate type wv, local cols nj*16+ln
    bf16x8 bfrag[2][16];
#pragma unroll
    for (int nj = 0; nj < 2; ++nj)
#pragma unroll
        for (int kc = 0; kc < 16; ++kc)
            bfrag[nj][kc] = *(const bf16x8*)
                &whh[(wv * 32 + nj * 16 + ln) * 512 + kc * 32 + quad * 8];
    __syncthreads();   // whh now dead; gst may alias

    const int b_pw = tid & 31;      // pointwise batch
    const int nl = tid >> 5;        // pointwise col group: cols 4nl..4nl+3
    const int b0 = quad * 4;
    const size_t preg0 = (size_t)(wv * 512 + w * 32 + ln);
    float c[4] = {0.f, 0.f, 0.f, 0.f};

    // register-prefetch pre[0]
    f32x4 pr[2][2];
#pragma unroll
    for (int mi = 0; mi < 2; ++mi)
#pragma unroll
        for (int nj = 0; nj < 2; ++nj)
            pr[mi][nj] = *(const f32x4*)
                &pre[((size_t)0 * G4 + preg0 + nj * 16) * BATCH + mi * 16 + b0];

    for (int t = 0; t < TT; ++t) {
        f32x4 acc[2][2];
#pragma unroll
        for (int mi = 0; mi < 2; ++mi)
#pragma unroll
            for (int nj = 0; nj < 2; ++nj)
                acc[mi][nj] = pr[mi][nj];

        u64 d[16][2][2];
        const __bf16* hb = Hall + (size_t)(t - 1) * BATCH * HH;
        if (t > 0) {
            // issue all 64 operand words (one pipelined LLC trip)
#pragma unroll
            for (int kc = 0; kc < 16; ++kc)
#pragma unroll
                for (int mi = 0; mi < 2; ++mi) {
                    const __bf16* p =
                        hb + (size_t)(mi * 16 + ln) * HH + kc * 32 + quad * 8;
                    d[kc][mi][0] = aload(p);
                    d[kc][mi][1] = aload(p + 4);
                }
        }

        // prefetch pre[t+1] (independent; overlaps polling)
        if (t + 1 < TT) {
#pragma unroll
            for (int mi = 0; mi < 2; ++mi)
#pragma unroll
                for (int nj = 0; nj < 2; ++nj)
                    pr[mi][nj] = *(const f32x4*)
                        &pre[((size_t)(t + 1) * G4 + preg0 + nj * 16) * BATCH +
                             mi * 16 + b0];
        }

        if (t > 0) {
            unsigned pend = 0xFFFFu;
            while (pend) {
#pragma unroll
                for (int kc = 0; kc < 16; ++kc) {
                    if (pend & (1u << kc)) {
                        bool cl = (d[kc][0][0] != POISON) &
                                  (d[kc][0][1] != POISON) &
                                  (d[kc][1][0] != POISON) &
                                  (d[kc][1][1] != POISON);
                        if (__all(cl)) {
                            union { u64 q[2]; bf16x8 v; } u0, u1;
                            u0.q[0] = d[kc][0][0]; u0.q[1] = d[kc][0][1];
                            u1.q[0] = d[kc][1][0]; u1.q[1] = d[kc][1][1];
                            acc[0][0] = MFMA(u0.v, bfrag[0][kc], acc[0][0]);
                            acc[0][1] = MFMA(u0.v, bfrag[1][kc], acc[0][1]);
                            acc[1][0] = MFMA(u1.v, bfrag[0][kc], acc[1][0]);
                            acc[1][1] = MFMA(u1.v, bfrag[1][kc], acc[1][1]);
                            pend &= ~(1u << kc);
                        }
                    }
                }
                if (pend) {
                    // reload only still-poisoned slices (one LLC trip, batched)
#pragma unroll
                    for (int kc = 0; kc < 16; ++kc) {
                        if (pend & (1u << kc)) {
#pragma unroll
                            for (int mi = 0; mi < 2; ++mi) {
                                const __bf16* p = hb +
                                    (size_t)(mi * 16 + ln) * HH + kc * 32 +
                                    quad * 8;
                                d[kc][mi][0] = aload(p);
                                d[kc][mi][1] = aload(p + 4);
                            }
                        }
                    }
                }
            }
        }

        __syncthreads();   // WAR: prev step's gst reads complete
#pragma unroll
        for (int mi = 0; mi < 2; ++mi)
#pragma unroll
            for (int nj = 0; nj < 2; ++nj)
                *(f32x4*)&gst[(wv * 32 + nj * 16 + ln) * 36 + mi * 16 + b0] =
                    acc[mi][nj];
        __syncthreads();

        // pointwise: 4 h-cols per thread, publish via packed u64 agent store
        union { u64 u; __bf16 h4[4]; } pk;
#pragma unroll
        for (int j = 0; j < 4; ++j) {
            int cl = nl * 4 + j;
            float gi = gst[(cl)      * 36 + b_pw];
            float gf = gst[(32 + cl) * 36 + b_pw];
            float gg = gst[(64 + cl) * 36 + b_pw];
            float go = gst[(96 + cl) * 36 + b_pw];
            c[j] = sigf(gf) * c[j] + sigf(gi) * tanh_fast(gg);
            pk.h4[j] = (__bf16)(sigf(go) * tanh_fast(c[j]));
        }
        __hip_atomic_store(
            (u64*)&Hall[((size_t)t * BATCH + b_pw) * HH + w * 32 + nl * 4],
            pk.u, __ATOMIC_RELAXED, __HIP_MEMORY_SCOPE_AGENT);
        // no drain, no flag: the data at the LLC IS the publication
    }
}

// ---------------------------------------------------------------------------
// Kernel C: out[b][t][n] = Hall[t*32+b][:] . Wfc[n][:] + bfc[n]   (fp32 out)
// BF16W=1: both operands bf16, staged via global_load_lds width-16.
// ---------------------------------------------------------------------------
template <int BF16W>
__global__ __launch_bounds__(256) void out_kernel(
    const __bf16* __restrict__ Hall, const float* __restrict__ Wfc,
    const __bf16* __restrict__ Wfc16, const float* __restrict__ bfc,
    float* __restrict__ out) {
    __shared__ __bf16 aT[128 * 32];
    __shared__ __bf16 bT[128 * 32];

    const int tid = threadIdx.x;
    const int mt = blockIdx.x;   // [0,16)
    const int nt = blockIdx.y;   // [0,235)
    const int lane = tid & 63, wv = tid >> 6;
    const int ln = lane & 15, quad = lane >> 4;
    const int wm = wv & 1, wn = wv >> 1;

    f32x4 acc[4][4] = {};
    const size_t aBase = (size_t)mt * 128 * HH;

    for (int kc = 0; kc < 16; ++kc) {
        const int k0 = kc * 32;
        if (BF16W) {
#pragma unroll
            for (int h = 0; h < 2; ++h) {
                int ch = tid + h * 256;            // chunk index, LDS byte = ch*16
                int r = ch >> 2, seg = ch & 3;
                const __bf16* asrc = &Hall[aBase + (size_t)r * HH + k0 + seg * 8];
                int gr = nt * 128 + r;
                if (gr >= VV) gr = VV - 1;         // clamp (stores guarded)
                const __bf16* bsrc = &Wfc16[(size_t)gr * HH + k0 + seg * 8];
                __builtin_amdgcn_global_load_lds(
                    (gvoid*)asrc,
                    (lvoid*)((char*)aT + wv * 1024 + h * 4096), 16, 0, 0);
                __builtin_amdgcn_global_load_lds(
                    (gvoid*)bsrc,
                    (lvoid*)((char*)bT + wv * 1024 + h * 4096), 16, 0, 0);
            }
        } else {
            for (int i = tid; i < 512; i += 256) {
                int r = i >> 2, seg = i & 3;
                *(bf16x8*)&aT[r * 32 + seg * 8] =
                    *(const bf16x8*)&Hall[aBase + (size_t)r * HH + k0 + seg * 8];
                int gr = nt * 128 + r;
                if (gr >= VV) gr = VV - 1;
                *(bf16x8*)&bT[r * 32 + seg * 8] =
                    cvt8(&Wfc[(size_t)gr * HH + k0 + seg * 8]);
            }
        }
        __syncthreads();
        bf16x8 af[4], bfr[4];
        for (int x = 0; x < 4; ++x) {
            af[x]  = *(const bf16x8*)&aT[(wm * 64 + x * 16 + ln) * 32 + quad * 8];
            bfr[x] = *(const bf16x8*)&bT[(wn * 64 + x * 16 + ln) * 32 + quad * 8];
        }
        for (int mi = 0; mi < 4; ++mi)
            for (int ni = 0; ni < 4; ++ni)
                acc[mi][ni] = MFMA(af[mi], bfr[ni], acc[mi][ni]);
        __syncthreads();
    }

    for (int ni = 0; ni < 4; ++ni) {
        int n = nt * 128 + wn * 64 + ni * 16 + ln;
        if (n >= VV) continue;
        float bias = bfc[n];
        for (int mi = 0; mi < 4; ++mi) {
            int m = mt * 128 + wm * 64 + mi * 16 + quad * 4;  // m = t*32+b
            for (int r = 0; r < 4; ++r) {
                int mm = m + r, t = mm >> 5, b = mm & 31;
                out[((size_t)b * TT + t) * VV + n] = acc[mi][ni][r] + bias;
            }
        }
    }
}

// ---------------------------------------------------------------------------
extern "C" void kernel_launch(void* const* d_in, const int* in_sizes, int n_in,
                              void* d_out, int out_size, void* d_ws, size_t ws_size,
                              hipStream_t stream) {
    const float* enc      = (const float*)d_in[0];
    const int*   captions = (const int*)d_in[1];
    // d_in[2..7]: We, be, Wd, bd, Wf, bf — dead (softmax over length-1 == 1)
    const float* emb      = (const float*)d_in[8];
    const float* Wih      = (const float*)d_in[9];
    const float* Whh      = (const float*)d_in[10];
    const float* bih      = (const float*)d_in[11];
    const float* bhh      = (const float*)d_in[12];
    const float* Wfc      = (const float*)d_in[13];
    const float* bfc      = (const float*)d_in[14];
    float* out = (float*)d_out;

    // pre (16.8 MB fp32) lives INSIDE d_out (245.8 MB fp32) — dead space until
    // out_kernel overwrites it, strictly after rnn_kernel consumed it.
    float* pre = (float*)d_out;

    uint8_t* w = (uint8_t*)d_ws;
    __bf16* Hall = (__bf16*)w;                       // [T][B][H] bf16 = 2 MiB
    const size_t HALL_BYTES = (size_t)TT * BATCH * HH * 2;       // 2,097,152
    const bool bf16w = ws_size >= HALL_BYTES + (size_t)VV * HH * 2;
    __bf16* Wfc16 = bf16w ? (__bf16*)(w + HALL_BYTES) : (__bf16*)nullptr;

    // poison Hall: 0xFFFF bf16 (-NaN) is unreachable for stored h values
    hipMemsetAsync(Hall, 0xFF, HALL_BYTES, stream);

    pre_kernel<<<dim3(16, 16), 256, 0, stream>>>(enc, captions, emb, Wih, bih, bhh, pre);
    rnn_kernel<<<dim3(256), 256, 0, stream>>>(pre, Whh, Hall, Wfc, Wfc16);
    if (bf16w)
        out_kernel<1><<<dim3(16, 235), 256, 0, stream>>>(Hall, Wfc, Wfc16, bfc, out);
    else
        out_kernel<0><<<dim3(16, 235), 256, 0, stream>>>(Hall, Wfc, Wfc16, bfc, out);
}

// Round 3
// 868.773 us; speedup vs baseline: 1.3332x; 1.3332x over previous
//
#include <hip/hip_runtime.h>
#include <hip/hip_bf16.h>

// DecoderRNN, fp32 in / fp32 out (reference dtypes), bf16 MFMA compute.
// Attention branch is dead code (softmax over a length-1 axis == 1 =>
// context == encoder_out; We/be/Wd/bd/Wf/bf never affect the output).
//   A) pre[t][g][b] = [emb(cap[b,t]), enc[b]] @ W_ih^T + b_ih + b_hh  (GEMM)
//      -> fp32 in WORKSPACE (d_out is live concurrently in the fused kernel)
//   B+C fused in ONE dispatch (256 WGs, 1 WG/CU, all co-resident):
//      WGs 0-15:   64-step LSTM recurrence (round-1 structure: Whh in VGPRs,
//                  sc1 write-through h stores + syncthreads vmcnt drain +
//                  per-WG flag publish; normal cacheable A-loads after poll).
//      WGs 16-255: out-GEMM consumers. Tile (mt,nt) of out = Hall @ Wfc^T
//                  needs only Hall rows [128mt,128mt+128) = steps 4mt..4mt+3,
//                  so consumers poll flags[4mt+3] and stream the 3760 tiles
//                  behind the recurrence wavefront (GEMM fully hidden).
// Fallback (small workspace): consumers exit, separate out_kernel afterwards,
// pre lives inside d_out (round-1 behavior).

#define BATCH 32
#define TT 64
#define VV 30000
#define HH 512
#define G4 2048     // 4*H
#define KX 768      // EMB + E
#define RNN_WG 16   // recurrence workgroups (128 gate rows each)
#define CONS_WG 240
#define NTILE 235   // ceil(30000/128)

typedef __bf16 bf16x8 __attribute__((ext_vector_type(8)));
typedef float f32x4 __attribute__((ext_vector_type(4)));
typedef unsigned long long u64;

#define MFMA(a, b, c) __builtin_amdgcn_mfma_f32_16x16x32_bf16((a), (b), (c), 0, 0, 0)

__device__ __forceinline__ float sigf(float x) {
    return 1.0f / (1.0f + __expf(-x));   // safe: x=+-inf -> 0/1
}
__device__ __forceinline__ float tanh_fast(float x) {
    return 1.0f - 2.0f / (__expf(2.0f * x) + 1.0f);   // safe at +-inf
}
__device__ __forceinline__ bf16x8 cvt8(const float* __restrict__ p) {
    const f32x4 a = *(const f32x4*)p;
    const f32x4 b = *(const f32x4*)(p + 4);
    bf16x8 r;
    r[0] = (__bf16)a[0]; r[1] = (__bf16)a[1]; r[2] = (__bf16)a[2]; r[3] = (__bf16)a[3];
    r[4] = (__bf16)b[0]; r[5] = (__bf16)b[1]; r[6] = (__bf16)b[2]; r[7] = (__bf16)b[3];
    return r;
}

// ---------------------------------------------------------------------------
// Kernel A: pre[t][g][b] fp32, layout [T][2048][32]. 128x128xK768 per WG.
// M index m = t*32 + b.  (unchanged)
// ---------------------------------------------------------------------------
__global__ __launch_bounds__(256) void pre_kernel(
    const float* __restrict__ enc, const int* __restrict__ captions,
    const float* __restrict__ emb, const float* __restrict__ Wih,
    const float* __restrict__ bih, const float* __restrict__ bhh,
    float* __restrict__ pre) {
    __shared__ __bf16 aT[128 * 32];
    __shared__ __bf16 bT[128 * 32];
    __shared__ int capm[128];

    const int tid = threadIdx.x;
    const int nt = blockIdx.x;   // gate tile [0,16)
    const int mt = blockIdx.y;   // token tile [0,16)

    if (tid < 128) {
        int m = mt * 128 + tid;               // m = t*32 + b
        capm[tid] = captions[(m & 31) * TT + (m >> 5)];
    }

    const int lane = tid & 63, wv = tid >> 6;
    const int ln = lane & 15, quad = lane >> 4;
    const int wm = wv & 1, wn = wv >> 1;

    f32x4 acc[4][4] = {};
    __syncthreads();

    for (int kc = 0; kc < 24; ++kc) {
        const int k0 = kc * 32;
        for (int i = tid; i < 512; i += 256) {
            int r = i >> 2, seg = i & 3;
            const float* src;
            if (k0 < 512) {
                src = emb + (size_t)capm[r] * 512 + k0 + seg * 8;
            } else {
                int b = (mt * 128 + r) & 31;
                src = enc + b * 256 + (k0 - 512) + seg * 8;
            }
            *(bf16x8*)&aT[r * 32 + seg * 8] = cvt8(src);
            *(bf16x8*)&bT[r * 32 + seg * 8] =
                cvt8(&Wih[(size_t)(nt * 128 + r) * KX + k0 + seg * 8]);
        }
        __syncthreads();
        bf16x8 af[4], bfr[4];
        for (int x = 0; x < 4; ++x) {
            af[x]  = *(const bf16x8*)&aT[(wm * 64 + x * 16 + ln) * 32 + quad * 8];
            bfr[x] = *(const bf16x8*)&bT[(wn * 64 + x * 16 + ln) * 32 + quad * 8];
        }
        for (int mi = 0; mi < 4; ++mi)
            for (int ni = 0; ni < 4; ++ni)
                acc[mi][ni] = MFMA(af[mi], bfr[ni], acc[mi][ni]);
        __syncthreads();
    }

    for (int ni = 0; ni < 4; ++ni) {
        int g = nt * 128 + wn * 64 + ni * 16 + ln;
        float bias = bih[g] + bhh[g];
        for (int mi = 0; mi < 4; ++mi) {
            int m = mt * 128 + wm * 64 + mi * 16 + quad * 4;  // m = t*32+b, b%4==0
            int t = m >> 5, b = m & 31;
            f32x4 v = acc[mi][ni];
            v[0] += bias; v[1] += bias; v[2] += bias; v[3] += bias;
            *(f32x4*)&pre[((size_t)t * G4 + g) * BATCH + b] = v;
        }
    }
}

// ---------------------------------------------------------------------------
// Fused kernel: recurrence producers (WGs 0-15) + out-GEMM consumers (16-255).
// Release protocol per step t (producer): packed-u64 relaxed-agent h stores
// (sc1 write-through => at LLC when vmcnt retires) -> __syncthreads (drains
// vmcnt in every wave) -> tid0 publishes flags[t*16+w]. Readers (producers at
// t+1 AND consumers) poll flags relaxed then read Hall with NORMAL cacheable
// loads — safe: Hall is write-once per launch and only ever read after its
// flag, so no cache anywhere can hold a pre-write copy of a line.
// ---------------------------------------------------------------------------
__global__ __launch_bounds__(256, 1) void fused_kernel(
    const float* __restrict__ pre, const float* __restrict__ Whh,
    __bf16* __restrict__ Hall, unsigned* __restrict__ flags,
    const float* __restrict__ Wfc, const float* __restrict__ bfc,
    float* __restrict__ out, int consume) {
    __shared__ char smem[131072];   // producers: whh staging / gst scratch
                                    // consumers: aT (8K) + bT (8K)
    const int tid = threadIdx.x;
    const int lane = tid & 63, wv = tid >> 6;
    const int ln = lane & 15, quad = lane >> 4;

    if (blockIdx.x >= RNN_WG) {
        // ================= consumer role: out-GEMM tiles =================
        if (!consume) return;
        __bf16* aT = (__bf16*)smem;            // [128][32]
        __bf16* bT = (__bf16*)(smem + 8192);   // [128][32]
        const int wm = wv & 1, wn = wv >> 1;
        const int cw = blockIdx.x - RNN_WG;

        for (int j = cw; j < 16 * NTILE; j += CONS_WG) {
            const int mt = j / NTILE, nt = j % NTILE;
            if (tid < RNN_WG) {
                const unsigned fidx = (unsigned)(mt * 4 + 3) * RNN_WG + tid;
                while (__hip_atomic_load(&flags[fidx], __ATOMIC_RELAXED,
                                         __HIP_MEMORY_SCOPE_AGENT) == 0)
                    __builtin_amdgcn_s_sleep(2);
            }
            __syncthreads();

            f32x4 acc[4][4] = {};
            const size_t aBase = (size_t)mt * 128 * HH;
            for (int kc = 0; kc < 16; ++kc) {
                const int k0 = kc * 32;
                for (int i = tid; i < 512; i += 256) {
                    int r = i >> 2, seg = i & 3;
                    *(bf16x8*)&aT[r * 32 + seg * 8] = *(const bf16x8*)
                        &Hall[aBase + (size_t)r * HH + k0 + seg * 8];
                    int gr = nt * 128 + r;
                    if (gr >= VV) gr = VV - 1;   // clamp (stores guarded)
                    *(bf16x8*)&bT[r * 32 + seg * 8] =
                        cvt8(&Wfc[(size_t)gr * HH + k0 + seg * 8]);
                }
                __syncthreads();
                bf16x8 af[4], bfr[4];
                for (int x = 0; x < 4; ++x) {
                    af[x]  = *(const bf16x8*)&aT[(wm * 64 + x * 16 + ln) * 32 + quad * 8];
                    bfr[x] = *(const bf16x8*)&bT[(wn * 64 + x * 16 + ln) * 32 + quad * 8];
                }
                for (int mi = 0; mi < 4; ++mi)
                    for (int ni = 0; ni < 4; ++ni)
                        acc[mi][ni] = MFMA(af[mi], bfr[ni], acc[mi][ni]);
                __syncthreads();
            }

            for (int ni = 0; ni < 4; ++ni) {
                int n = nt * 128 + wn * 64 + ni * 16 + ln;
                if (n >= VV) continue;
                float bias = bfc[n];
                for (int mi = 0; mi < 4; ++mi) {
                    int m = mt * 128 + wm * 64 + mi * 16 + quad * 4;  // m=t*32+b
                    for (int r = 0; r < 4; ++r) {
                        int mm = m + r, t = mm >> 5, b = mm & 31;
                        out[((size_t)b * TT + t) * VV + n] = acc[mi][ni][r] + bias;
                    }
                }
            }
        }
        return;
    }

    // ==================== producer role: LSTM recurrence ====================
    __bf16* whh = (__bf16*)smem;    // [128][512] — dead after fragment hoist
    float*  gst = (float*)smem;     // [128][36]  — aliases whh afterwards
    const int w = blockIdx.x;

    // stage Whh slice (row r: gate type r>>5, h-col w*32+(r&31)), fp32->bf16
    for (int i = tid; i < 128 * 64; i += 256) {
        int r = i >> 6, k = (i & 63) << 3;
        int g = (r >> 5) * 512 + w * 32 + (r & 31);
        *(bf16x8*)&whh[r * 512 + k] = cvt8(&Whh[(size_t)g * HH + k]);
    }
    __syncthreads();

    // hoist B fragments: wave wv = gate type wv, local cols nj*16+ln
    bf16x8 bfrag[2][16];
#pragma unroll
    for (int nj = 0; nj < 2; ++nj)
#pragma unroll
        for (int kc = 0; kc < 16; ++kc)
            bfrag[nj][kc] = *(const bf16x8*)
                &whh[(wv * 32 + nj * 16 + ln) * 512 + kc * 32 + quad * 8];
    __syncthreads();   // whh now dead; gst may alias

    const int b_pw = tid & 31;      // pointwise batch
    const int nl = tid >> 5;        // pointwise col group: cols 4nl..4nl+3
    const int b0 = quad * 4;
    const size_t preg0 = (size_t)(wv * 512 + w * 32 + ln);
    float c[4] = {0.f, 0.f, 0.f, 0.f};

    // register-prefetch pre[0]
    f32x4 pr[2][2];
#pragma unroll
    for (int mi = 0; mi < 2; ++mi)
#pragma unroll
        for (int nj = 0; nj < 2; ++nj)
            pr[mi][nj] = *(const f32x4*)
                &pre[(preg0 + nj * 16) * BATCH + mi * 16 + b0];

    for (int t = 0; t < TT; ++t) {
        f32x4 acc[2][2];
#pragma unroll
        for (int mi = 0; mi < 2; ++mi)
#pragma unroll
            for (int nj = 0; nj < 2; ++nj)
                acc[mi][nj] = pr[mi][nj];

        // prefetch pre[t+1] before the poll (independent; overlaps waiting)
        if (t + 1 < TT) {
#pragma unroll
            for (int mi = 0; mi < 2; ++mi)
#pragma unroll
                for (int nj = 0; nj < 2; ++nj)
                    pr[mi][nj] = *(const f32x4*)
                        &pre[((size_t)(t + 1) * G4 + preg0 + nj * 16) * BATCH +
                             mi * 16 + b0];
        }

        if (t > 0) {
            if (tid < RNN_WG) {
                while (__hip_atomic_load(&flags[(t - 1) * RNN_WG + tid],
                                         __ATOMIC_RELAXED,
                                         __HIP_MEMORY_SCOPE_AGENT) == 0) {}
            }
        }
        __syncthreads();   // join pollers; WAR fence for gst reuse

        if (t > 0) {
            const __bf16* hbase = Hall + (size_t)(t - 1) * BATCH * HH;
            bf16x8 a[2][8];
#pragma unroll
            for (int half = 0; half < 2; ++half) {
#pragma unroll
                for (int mi = 0; mi < 2; ++mi)
#pragma unroll
                    for (int kk = 0; kk < 8; ++kk)
                        a[mi][kk] = *(const bf16x8*)
                            &hbase[(size_t)(mi * 16 + ln) * HH +
                                   (half * 8 + kk) * 32 + quad * 8];
#pragma unroll
                for (int kk = 0; kk < 8; ++kk)
#pragma unroll
                    for (int mi = 0; mi < 2; ++mi)
#pragma unroll
                        for (int nj = 0; nj < 2; ++nj)
                            acc[mi][nj] = MFMA(a[mi][kk],
                                               bfrag[nj][half * 8 + kk],
                                               acc[mi][nj]);
            }
        }
#pragma unroll
        for (int mi = 0; mi < 2; ++mi)
#pragma unroll
            for (int nj = 0; nj < 2; ++nj)
                *(f32x4*)&gst[(wv * 32 + nj * 16 + ln) * 36 + mi * 16 + b0] =
                    acc[mi][nj];
        __syncthreads();

        // pointwise: 4 h-cols per thread, publish via packed u64 agent store
        union { u64 u; __bf16 h4[4]; } pk;
#pragma unroll
        for (int j = 0; j < 4; ++j) {
            int cl = nl * 4 + j;
            float gi = gst[(cl)      * 36 + b_pw];
            float gf = gst[(32 + cl) * 36 + b_pw];
            float gg = gst[(64 + cl) * 36 + b_pw];
            float go = gst[(96 + cl) * 36 + b_pw];
            c[j] = sigf(gf) * c[j] + sigf(gi) * tanh_fast(gg);
            pk.h4[j] = (__bf16)(sigf(go) * tanh_fast(c[j]));
        }
        __hip_atomic_store(
            (u64*)&Hall[((size_t)t * BATCH + b_pw) * HH + w * 32 + nl * 4],
            pk.u, __ATOMIC_RELAXED, __HIP_MEMORY_SCOPE_AGENT);

        __syncthreads();   // every wave drains vmcnt => all h-stores at LLC
        if (tid == 0)
            __hip_atomic_store(&flags[t * RNN_WG + w], 1u, __ATOMIC_RELAXED,
                               __HIP_MEMORY_SCOPE_AGENT);
    }
}

// ---------------------------------------------------------------------------
// Fallback kernel C (only if workspace too small for fused pre placement):
// out[b][t][n] = Hall[t*32+b][:] . Wfc[n][:] + bfc[n]   (fp32 out)
// ---------------------------------------------------------------------------
__global__ __launch_bounds__(256) void out_kernel(
    const __bf16* __restrict__ Hall, const float* __restrict__ Wfc,
    const float* __restrict__ bfc, float* __restrict__ out) {
    __shared__ __bf16 aT[128 * 32];
    __shared__ __bf16 bT[128 * 32];

    const int tid = threadIdx.x;
    const int mt = blockIdx.x;   // [0,16)
    const int nt = blockIdx.y;   // [0,235)
    const int lane = tid & 63, wv = tid >> 6;
    const int ln = lane & 15, quad = lane >> 4;
    const int wm = wv & 1, wn = wv >> 1;

    f32x4 acc[4][4] = {};
    const size_t aBase = (size_t)mt * 128 * HH;

    for (int kc = 0; kc < 16; ++kc) {
        const int k0 = kc * 32;
        for (int i = tid; i < 512; i += 256) {
            int r = i >> 2, seg = i & 3;
            *(bf16x8*)&aT[r * 32 + seg * 8] =
                *(const bf16x8*)&Hall[aBase + (size_t)r * HH + k0 + seg * 8];
            int gr = nt * 128 + r;
            if (gr >= VV) gr = VV - 1;
            *(bf16x8*)&bT[r * 32 + seg * 8] =
                cvt8(&Wfc[(size_t)gr * HH + k0 + seg * 8]);
        }
        __syncthreads();
        bf16x8 af[4], bfr[4];
        for (int x = 0; x < 4; ++x) {
            af[x]  = *(const bf16x8*)&aT[(wm * 64 + x * 16 + ln) * 32 + quad * 8];
            bfr[x] = *(const bf16x8*)&bT[(wn * 64 + x * 16 + ln) * 32 + quad * 8];
        }
        for (int mi = 0; mi < 4; ++mi)
            for (int ni = 0; ni < 4; ++ni)
                acc[mi][ni] = MFMA(af[mi], bfr[ni], acc[mi][ni]);
        __syncthreads();
    }

    for (int ni = 0; ni < 4; ++ni) {
        int n = nt * 128 + wn * 64 + ni * 16 + ln;
        if (n >= VV) continue;
        float bias = bfc[n];
        for (int mi = 0; mi < 4; ++mi) {
            int m = mt * 128 + wm * 64 + mi * 16 + quad * 4;  // m = t*32+b
            for (int r = 0; r < 4; ++r) {
                int mm = m + r, t = mm >> 5, b = mm & 31;
                out[((size_t)b * TT + t) * VV + n] = acc[mi][ni][r] + bias;
            }
        }
    }
}

// ---------------------------------------------------------------------------
extern "C" void kernel_launch(void* const* d_in, const int* in_sizes, int n_in,
                              void* d_out, int out_size, void* d_ws, size_t ws_size,
                              hipStream_t stream) {
    const float* enc      = (const float*)d_in[0];
    const int*   captions = (const int*)d_in[1];
    // d_in[2..7]: We, be, Wd, bd, Wf, bf — dead (softmax over length-1 == 1)
    const float* emb      = (const float*)d_in[8];
    const float* Wih      = (const float*)d_in[9];
    const float* Whh      = (const float*)d_in[10];
    const float* bih      = (const float*)d_in[11];
    const float* bhh      = (const float*)d_in[12];
    const float* Wfc      = (const float*)d_in[13];
    const float* bfc      = (const float*)d_in[14];
    float* out = (float*)d_out;

    uint8_t* w = (uint8_t*)d_ws;
    unsigned* flags = (unsigned*)w;                  // 64*16 u32 (16 KiB rsvd)
    __bf16* Hall = (__bf16*)(w + 16384);             // [T][B][H] bf16 = 2 MiB
    const size_t PRE_OFF   = 16384 + (size_t)TT * BATCH * HH * 2;   // 2,113,536
    const size_t PRE_BYTES = (size_t)TT * G4 * BATCH * 4;           // 16,777,216
    const bool fused = ws_size >= PRE_OFF + PRE_BYTES;              // ~18.9 MB

    // Fused: pre in workspace (d_out is written concurrently by consumers).
    // Fallback: pre inside d_out (dead space until serial out_kernel).
    float* pre = fused ? (float*)(w + PRE_OFF) : (float*)d_out;

    hipMemsetAsync(flags, 0, 16384, stream);         // ws is poisoned each launch

    pre_kernel<<<dim3(16, 16), 256, 0, stream>>>(enc, captions, emb, Wih, bih, bhh, pre);
    fused_kernel<<<dim3(256), 256, 0, stream>>>(pre, Whh, Hall, flags, Wfc, bfc,
                                                out, fused ? 1 : 0);
    if (!fused)
        out_kernel<<<dim3(16, 235), 256, 0, stream>>>(Hall, Wfc, bfc, out);
}

// Round 4
// 864.303 us; speedup vs baseline: 1.3401x; 1.0052x over previous
//
#include <hip/hip_runtime.h>
#include <hip/hip_bf16.h>

// DecoderRNN, fp32 in / fp32 out (reference dtypes), bf16 MFMA compute.
// Attention branch is dead code (softmax over a length-1 axis == 1 =>
// context == encoder_out; We/be/Wd/bd/Wf/bf never affect the output).
// ONE fused dispatch (256 WGs, 1 WG/CU, all co-resident):
//   WGs 16-255 (consumers), phase 1: pre[t][g][b] = [emb,enc] @ W_ih^T + bias
//     tiles (mt-major order), published via write-through u64 stores +
//     vmcnt-drain + preCtr[mt] atomicAdd.
//   WGs 0-15 (producers): 64-step LSTM recurrence; Whh in VGPRs; sc1
//     write-through h stores + syncthreads drain + per-WG flag publish;
//     normal cacheable A-loads after flag. pre[t] register-prefetched,
//     guarded by a once-per-mt acquire poll of preCtr.
//   WGs 16-255, phase 2: out = Hall @ W_fc^T + b_fc tiles, gated on
//     flags[4mt+3] — streamed behind the recurrence wavefront (hidden).
// Fallback (small workspace): separate pre_kernel / out_kernel, pre in d_out.

#define BATCH 32
#define TT 64
#define VV 30000
#define HH 512
#define G4 2048     // 4*H
#define KX 768      // EMB + E
#define RNN_WG 16   // recurrence workgroups (128 gate rows each)
#define CONS_WG 240
#define NTILE 235   // ceil(30000/128)

typedef __bf16 bf16x8 __attribute__((ext_vector_type(8)));
typedef float f32x4 __attribute__((ext_vector_type(4)));
typedef unsigned long long u64;

#define MFMA(a, b, c) __builtin_amdgcn_mfma_f32_16x16x32_bf16((a), (b), (c), 0, 0, 0)

__device__ __forceinline__ float sigf(float x) {
    return 1.0f / (1.0f + __expf(-x));   // safe: x=+-inf -> 0/1
}
__device__ __forceinline__ float tanh_fast(float x) {
    return 1.0f - 2.0f / (__expf(2.0f * x) + 1.0f);   // safe at +-inf
}
__device__ __forceinline__ bf16x8 cvt8(const float* __restrict__ p) {
    const f32x4 a = *(const f32x4*)p;
    const f32x4 b = *(const f32x4*)(p + 4);
    bf16x8 r;
    r[0] = (__bf16)a[0]; r[1] = (__bf16)a[1]; r[2] = (__bf16)a[2]; r[3] = (__bf16)a[3];
    r[4] = (__bf16)b[0]; r[5] = (__bf16)b[1]; r[6] = (__bf16)b[2]; r[7] = (__bf16)b[3];
    return r;
}

// ---------------------------------------------------------------------------
// Standalone kernel A (FALLBACK ONLY): pre[t][g][b] fp32, [T][2048][32].
// ---------------------------------------------------------------------------
__global__ __launch_bounds__(256) void pre_kernel(
    const float* __restrict__ enc, const int* __restrict__ captions,
    const float* __restrict__ emb, const float* __restrict__ Wih,
    const float* __restrict__ bih, const float* __restrict__ bhh,
    float* __restrict__ pre) {
    __shared__ __bf16 aT[128 * 32];
    __shared__ __bf16 bT[128 * 32];
    __shared__ int capm[128];

    const int tid = threadIdx.x;
    const int nt = blockIdx.x;   // gate tile [0,16)
    const int mt = blockIdx.y;   // token tile [0,16)

    if (tid < 128) {
        int m = mt * 128 + tid;               // m = t*32 + b
        capm[tid] = captions[(m & 31) * TT + (m >> 5)];
    }

    const int lane = tid & 63, wv = tid >> 6;
    const int ln = lane & 15, quad = lane >> 4;
    const int wm = wv & 1, wn = wv >> 1;

    f32x4 acc[4][4] = {};
    __syncthreads();

    for (int kc = 0; kc < 24; ++kc) {
        const int k0 = kc * 32;
        for (int i = tid; i < 512; i += 256) {
            int r = i >> 2, seg = i & 3;
            const float* src;
            if (k0 < 512) {
                src = emb + (size_t)capm[r] * 512 + k0 + seg * 8;
            } else {
                int b = (mt * 128 + r) & 31;
                src = enc + b * 256 + (k0 - 512) + seg * 8;
            }
            *(bf16x8*)&aT[r * 32 + seg * 8] = cvt8(src);
            *(bf16x8*)&bT[r * 32 + seg * 8] =
                cvt8(&Wih[(size_t)(nt * 128 + r) * KX + k0 + seg * 8]);
        }
        __syncthreads();
        bf16x8 af[4], bfr[4];
        for (int x = 0; x < 4; ++x) {
            af[x]  = *(const bf16x8*)&aT[(wm * 64 + x * 16 + ln) * 32 + quad * 8];
            bfr[x] = *(const bf16x8*)&bT[(wn * 64 + x * 16 + ln) * 32 + quad * 8];
        }
        for (int mi = 0; mi < 4; ++mi)
            for (int ni = 0; ni < 4; ++ni)
                acc[mi][ni] = MFMA(af[mi], bfr[ni], acc[mi][ni]);
        __syncthreads();
    }

    for (int ni = 0; ni < 4; ++ni) {
        int g = nt * 128 + wn * 64 + ni * 16 + ln;
        float bias = bih[g] + bhh[g];
        for (int mi = 0; mi < 4; ++mi) {
            int m = mt * 128 + wm * 64 + mi * 16 + quad * 4;  // m = t*32+b, b%4==0
            int t = m >> 5, b = m & 31;
            f32x4 v = acc[mi][ni];
            v[0] += bias; v[1] += bias; v[2] += bias; v[3] += bias;
            *(f32x4*)&pre[((size_t)t * G4 + g) * BATCH + b] = v;
        }
    }
}

// ---------------------------------------------------------------------------
// Fused kernel. Release protocol everywhere: write-through relaxed-agent
// atomic stores (at LLC when vmcnt retires) -> __syncthreads (drains vmcnt in
// every wave) -> publish counter/flag. Readers poll relaxed then read with
// normal cacheable loads (all published buffers are write-once per launch and
// only read after their flag => no stale cached copies can exist).
// ---------------------------------------------------------------------------
__global__ __launch_bounds__(256, 1) void fused_kernel(
    const float* __restrict__ enc, const int* __restrict__ captions,
    const float* __restrict__ emb, const float* __restrict__ Wih,
    const float* __restrict__ bih, const float* __restrict__ bhh,
    float* __restrict__ pre, const float* __restrict__ Whh,
    __bf16* __restrict__ Hall, unsigned* __restrict__ flags,
    unsigned* __restrict__ preCtr,
    const float* __restrict__ Wfc, const float* __restrict__ bfc,
    float* __restrict__ out, int fused) {
    __shared__ char smem[131072];
    const int tid = threadIdx.x;
    const int lane = tid & 63, wv = tid >> 6;
    const int ln = lane & 15, quad = lane >> 4;

    if (blockIdx.x >= RNN_WG) {
        // ======================= consumer role =======================
        if (!fused) return;
        __bf16* aT = (__bf16*)smem;            // [128][32]
        __bf16* bT = (__bf16*)(smem + 8192);   // [128][32]
        int* capm  = (int*)(smem + 16384);     // [128]
        const int wm = wv & 1, wn = wv >> 1;
        const int cw = blockIdx.x - RNN_WG;

        // ---- phase 1: pre tiles (mt-major: j = mt*16 + nt) ----
        for (int j = cw; j < 256; j += CONS_WG) {
            const int mtp = j >> 4, ntp = j & 15;
            if (tid < 128) {
                int m = mtp * 128 + tid;       // m = t*32 + b
                capm[tid] = captions[(m & 31) * TT + (m >> 5)];
            }
            f32x4 acc[4][4] = {};
            __syncthreads();

            for (int kc = 0; kc < 24; ++kc) {
                const int k0 = kc * 32;
                for (int i = tid; i < 512; i += 256) {
                    int r = i >> 2, seg = i & 3;
                    const float* src;
                    if (k0 < 512) {
                        src = emb + (size_t)capm[r] * 512 + k0 + seg * 8;
                    } else {
                        int b = (mtp * 128 + r) & 31;
                        src = enc + b * 256 + (k0 - 512) + seg * 8;
                    }
                    *(bf16x8*)&aT[r * 32 + seg * 8] = cvt8(src);
                    *(bf16x8*)&bT[r * 32 + seg * 8] =
                        cvt8(&Wih[(size_t)(ntp * 128 + r) * KX + k0 + seg * 8]);
                }
                __syncthreads();
                bf16x8 af[4], bfr[4];
                for (int x = 0; x < 4; ++x) {
                    af[x]  = *(const bf16x8*)&aT[(wm * 64 + x * 16 + ln) * 32 + quad * 8];
                    bfr[x] = *(const bf16x8*)&bT[(wn * 64 + x * 16 + ln) * 32 + quad * 8];
                }
                for (int mi = 0; mi < 4; ++mi)
                    for (int ni = 0; ni < 4; ++ni)
                        acc[mi][ni] = MFMA(af[mi], bfr[ni], acc[mi][ni]);
                __syncthreads();
            }

            for (int ni = 0; ni < 4; ++ni) {
                int g = ntp * 128 + wn * 64 + ni * 16 + ln;
                float bias = bih[g] + bhh[g];
                for (int mi = 0; mi < 4; ++mi) {
                    int m = mtp * 128 + wm * 64 + mi * 16 + quad * 4;  // b%4==0
                    int t = m >> 5, b = m & 31;
                    union { f32x4 v; u64 q[2]; } uu;
                    uu.v = acc[mi][ni];
                    uu.v[0] += bias; uu.v[1] += bias;
                    uu.v[2] += bias; uu.v[3] += bias;
                    u64* dst = (u64*)&pre[((size_t)t * G4 + g) * BATCH + b];
                    __hip_atomic_store(dst, uu.q[0], __ATOMIC_RELAXED,
                                       __HIP_MEMORY_SCOPE_AGENT);
                    __hip_atomic_store(dst + 1, uu.q[1], __ATOMIC_RELAXED,
                                       __HIP_MEMORY_SCOPE_AGENT);
                }
            }
            __syncthreads();   // drain all waves' vmcnt => tile at LLC
            if (tid == 0)
                __hip_atomic_fetch_add(&preCtr[mtp], 1u, __ATOMIC_RELAXED,
                                       __HIP_MEMORY_SCOPE_AGENT);
        }

        // ---- phase 2: out tiles, gated on recurrence flags ----
        for (int j = cw; j < 16 * NTILE; j += CONS_WG) {
            const int mt = j / NTILE, nt = j % NTILE;
            if (tid < RNN_WG) {
                const unsigned fidx = (unsigned)(mt * 4 + 3) * RNN_WG + tid;
                while (__hip_atomic_load(&flags[fidx], __ATOMIC_RELAXED,
                                         __HIP_MEMORY_SCOPE_AGENT) == 0)
                    __builtin_amdgcn_s_sleep(2);
            }
            __syncthreads();

            f32x4 acc[4][4] = {};
            const size_t aBase = (size_t)mt * 128 * HH;
            for (int kc = 0; kc < 16; ++kc) {
                const int k0 = kc * 32;
                for (int i = tid; i < 512; i += 256) {
                    int r = i >> 2, seg = i & 3;
                    *(bf16x8*)&aT[r * 32 + seg * 8] = *(const bf16x8*)
                        &Hall[aBase + (size_t)r * HH + k0 + seg * 8];
                    int gr = nt * 128 + r;
                    if (gr >= VV) gr = VV - 1;   // clamp (stores guarded)
                    *(bf16x8*)&bT[r * 32 + seg * 8] =
                        cvt8(&Wfc[(size_t)gr * HH + k0 + seg * 8]);
                }
                __syncthreads();
                bf16x8 af[4], bfr[4];
                for (int x = 0; x < 4; ++x) {
                    af[x]  = *(const bf16x8*)&aT[(wm * 64 + x * 16 + ln) * 32 + quad * 8];
                    bfr[x] = *(const bf16x8*)&bT[(wn * 64 + x * 16 + ln) * 32 + quad * 8];
                }
                for (int mi = 0; mi < 4; ++mi)
                    for (int ni = 0; ni < 4; ++ni)
                        acc[mi][ni] = MFMA(af[mi], bfr[ni], acc[mi][ni]);
                __syncthreads();
            }

            for (int ni = 0; ni < 4; ++ni) {
                int n = nt * 128 + wn * 64 + ni * 16 + ln;
                if (n >= VV) continue;
                float bias = bfc[n];
                for (int mi = 0; mi < 4; ++mi) {
                    int m = mt * 128 + wm * 64 + mi * 16 + quad * 4;  // m=t*32+b
                    for (int r = 0; r < 4; ++r) {
                        int mm = m + r, t = mm >> 5, b = mm & 31;
                        out[((size_t)b * TT + t) * VV + n] = acc[mi][ni][r] + bias;
                    }
                }
            }
        }
        return;
    }

    // ==================== producer role: LSTM recurrence ====================
    __bf16* whh = (__bf16*)smem;    // [128][512] — dead after fragment hoist
    float*  gst = (float*)smem;     // [128][36]  — aliases whh afterwards
    const int w = blockIdx.x;

    // stage Whh slice (row r: gate type r>>5, h-col w*32+(r&31)), fp32->bf16
    for (int i = tid; i < 128 * 64; i += 256) {
        int r = i >> 6, k = (i & 63) << 3;
        int g = (r >> 5) * 512 + w * 32 + (r & 31);
        *(bf16x8*)&whh[r * 512 + k] = cvt8(&Whh[(size_t)g * HH + k]);
    }
    __syncthreads();

    // hoist B fragments: wave wv = gate type wv, local cols nj*16+ln
    bf16x8 bfrag[2][16];
#pragma unroll
    for (int nj = 0; nj < 2; ++nj)
#pragma unroll
        for (int kc = 0; kc < 16; ++kc)
            bfrag[nj][kc] = *(const bf16x8*)
                &whh[(wv * 32 + nj * 16 + ln) * 512 + kc * 32 + quad * 8];
    __syncthreads();   // whh now dead; gst may alias

    const int b_pw = tid & 31;      // pointwise batch
    const int nl = tid >> 5;        // pointwise col group: cols 4nl..4nl+3
    const int b0 = quad * 4;
    const size_t preg0 = (size_t)(wv * 512 + w * 32 + ln);
    float c[4] = {0.f, 0.f, 0.f, 0.f};
    unsigned doneMask = 1u;         // preCtr[mt] groups confirmed complete

    if (fused) {
        if (tid == 0) {
            while (__hip_atomic_load(&preCtr[0], __ATOMIC_RELAXED,
                                     __HIP_MEMORY_SCOPE_AGENT) < 16u) {}
        }
        __syncthreads();   // orders all threads' pre[0] loads after publish
    }

    // register-prefetch pre[0]
    f32x4 pr[2][2];
#pragma unroll
    for (int mi = 0; mi < 2; ++mi)
#pragma unroll
        for (int nj = 0; nj < 2; ++nj)
            pr[mi][nj] = *(const f32x4*)
                &pre[(preg0 + nj * 16) * BATCH + mi * 16 + b0];

    for (int t = 0; t < TT; ++t) {
        f32x4 acc[2][2];
#pragma unroll
        for (int mi = 0; mi < 2; ++mi)
#pragma unroll
            for (int nj = 0; nj < 2; ++nj)
                acc[mi][nj] = pr[mi][nj];

        // prefetch pre[t+1] before the poll (independent; overlaps waiting)
        if (t + 1 < TT) {
            const int mt2 = (t + 1) >> 2;
            if (fused && !(doneMask & (1u << mt2))) {
                // acquire: orders each thread's subsequent pre loads
                while (__hip_atomic_load(&preCtr[mt2], __ATOMIC_ACQUIRE,
                                         __HIP_MEMORY_SCOPE_AGENT) < 16u) {}
                doneMask |= 1u << mt2;
            }
#pragma unroll
            for (int mi = 0; mi < 2; ++mi)
#pragma unroll
                for (int nj = 0; nj < 2; ++nj)
                    pr[mi][nj] = *(const f32x4*)
                        &pre[((size_t)(t + 1) * G4 + preg0 + nj * 16) * BATCH +
                             mi * 16 + b0];
        }

        if (t > 0) {
            if (tid < RNN_WG) {
                while (__hip_atomic_load(&flags[(t - 1) * RNN_WG + tid],
                                         __ATOMIC_RELAXED,
                                         __HIP_MEMORY_SCOPE_AGENT) == 0) {}
            }
        }
        __syncthreads();   // join pollers; WAR fence for gst reuse

        if (t > 0) {
            const __bf16* hbase = Hall + (size_t)(t - 1) * BATCH * HH;
            bf16x8 a[2][8];
#pragma unroll
            for (int half = 0; half < 2; ++half) {
#pragma unroll
                for (int mi = 0; mi < 2; ++mi)
#pragma unroll
                    for (int kk = 0; kk < 8; ++kk)
                        a[mi][kk] = *(const bf16x8*)
                            &hbase[(size_t)(mi * 16 + ln) * HH +
                                   (half * 8 + kk) * 32 + quad * 8];
#pragma unroll
                for (int kk = 0; kk < 8; ++kk)
#pragma unroll
                    for (int mi = 0; mi < 2; ++mi)
#pragma unroll
                        for (int nj = 0; nj < 2; ++nj)
                            acc[mi][nj] = MFMA(a[mi][kk],
                                               bfrag[nj][half * 8 + kk],
                                               acc[mi][nj]);
            }
        }
#pragma unroll
        for (int mi = 0; mi < 2; ++mi)
#pragma unroll
            for (int nj = 0; nj < 2; ++nj)
                *(f32x4*)&gst[(wv * 32 + nj * 16 + ln) * 36 + mi * 16 + b0] =
                    acc[mi][nj];
        __syncthreads();

        // pointwise: 4 h-cols per thread, publish via packed u64 agent store
        union { u64 u; __bf16 h4[4]; } pk;
#pragma unroll
        for (int j = 0; j < 4; ++j) {
            int cl = nl * 4 + j;
            float gi = gst[(cl)      * 36 + b_pw];
            float gf = gst[(32 + cl) * 36 + b_pw];
            float gg = gst[(64 + cl) * 36 + b_pw];
            float go = gst[(96 + cl) * 36 + b_pw];
            c[j] = sigf(gf) * c[j] + sigf(gi) * tanh_fast(gg);
            pk.h4[j] = (__bf16)(sigf(go) * tanh_fast(c[j]));
        }
        __hip_atomic_store(
            (u64*)&Hall[((size_t)t * BATCH + b_pw) * HH + w * 32 + nl * 4],
            pk.u, __ATOMIC_RELAXED, __HIP_MEMORY_SCOPE_AGENT);

        __syncthreads();   // every wave drains vmcnt => all h-stores at LLC
        if (tid == 0)
            __hip_atomic_store(&flags[t * RNN_WG + w], 1u, __ATOMIC_RELAXED,
                               __HIP_MEMORY_SCOPE_AGENT);
    }
}

// ---------------------------------------------------------------------------
// Fallback kernel C (only if workspace too small):
// out[b][t][n] = Hall[t*32+b][:] . Wfc[n][:] + bfc[n]   (fp32 out)
// ---------------------------------------------------------------------------
__global__ __launch_bounds__(256) void out_kernel(
    const __bf16* __restrict__ Hall, const float* __restrict__ Wfc,
    const float* __restrict__ bfc, float* __restrict__ out) {
    __shared__ __bf16 aT[128 * 32];
    __shared__ __bf16 bT[128 * 32];

    const int tid = threadIdx.x;
    const int mt = blockIdx.x;   // [0,16)
    const int nt = blockIdx.y;   // [0,235)
    const int lane = tid & 63, wv = tid >> 6;
    const int ln = lane & 15, quad = lane >> 4;
    const int wm = wv & 1, wn = wv >> 1;

    f32x4 acc[4][4] = {};
    const size_t aBase = (size_t)mt * 128 * HH;

    for (int kc = 0; kc < 16; ++kc) {
        const int k0 = kc * 32;
        for (int i = tid; i < 512; i += 256) {
            int r = i >> 2, seg = i & 3;
            *(bf16x8*)&aT[r * 32 + seg * 8] =
                *(const bf16x8*)&Hall[aBase + (size_t)r * HH + k0 + seg * 8];
            int gr = nt * 128 + r;
            if (gr >= VV) gr = VV - 1;
            *(bf16x8*)&bT[r * 32 + seg * 8] =
                cvt8(&Wfc[(size_t)gr * HH + k0 + seg * 8]);
        }
        __syncthreads();
        bf16x8 af[4], bfr[4];
        for (int x = 0; x < 4; ++x) {
            af[x]  = *(const bf16x8*)&aT[(wm * 64 + x * 16 + ln) * 32 + quad * 8];
            bfr[x] = *(const bf16x8*)&bT[(wn * 64 + x * 16 + ln) * 32 + quad * 8];
        }
        for (int mi = 0; mi < 4; ++mi)
            for (int ni = 0; ni < 4; ++ni)
                acc[mi][ni] = MFMA(af[mi], bfr[ni], acc[mi][ni]);
        __syncthreads();
    }

    for (int ni = 0; ni < 4; ++ni) {
        int n = nt * 128 + wn * 64 + ni * 16 + ln;
        if (n >= VV) continue;
        float bias = bfc[n];
        for (int mi = 0; mi < 4; ++mi) {
            int m = mt * 128 + wm * 64 + mi * 16 + quad * 4;  // m = t*32+b
            for (int r = 0; r < 4; ++r) {
                int mm = m + r, t = mm >> 5, b = mm & 31;
                out[((size_t)b * TT + t) * VV + n] = acc[mi][ni][r] + bias;
            }
        }
    }
}

// ---------------------------------------------------------------------------
extern "C" void kernel_launch(void* const* d_in, const int* in_sizes, int n_in,
                              void* d_out, int out_size, void* d_ws, size_t ws_size,
                              hipStream_t stream) {
    const float* enc      = (const float*)d_in[0];
    const int*   captions = (const int*)d_in[1];
    // d_in[2..7]: We, be, Wd, bd, Wf, bf — dead (softmax over length-1 == 1)
    const float* emb      = (const float*)d_in[8];
    const float* Wih      = (const float*)d_in[9];
    const float* Whh      = (const float*)d_in[10];
    const float* bih      = (const float*)d_in[11];
    const float* bhh      = (const float*)d_in[12];
    const float* Wfc      = (const float*)d_in[13];
    const float* bfc      = (const float*)d_in[14];
    float* out = (float*)d_out;

    uint8_t* w = (uint8_t*)d_ws;
    unsigned* flags  = (unsigned*)w;                 // 64*16 u32 = 4 KiB
    unsigned* preCtr = (unsigned*)(w + 4096);        // 16 u32
    __bf16* Hall = (__bf16*)(w + 16384);             // [T][B][H] bf16 = 2 MiB
    const size_t PRE_OFF   = 16384 + (size_t)TT * BATCH * HH * 2;   // 2,113,536
    const size_t PRE_BYTES = (size_t)TT * G4 * BATCH * 4;           // 16,777,216
    const bool fused = ws_size >= PRE_OFF + PRE_BYTES;              // ~18.9 MB

    // Fused: pre in workspace (d_out is written concurrently by consumers).
    // Fallback: pre inside d_out (dead space until serial out_kernel).
    float* pre = fused ? (float*)(w + PRE_OFF) : (float*)d_out;

    hipMemsetAsync(flags, 0, 16384, stream);         // flags + preCtr

    if (!fused)
        pre_kernel<<<dim3(16, 16), 256, 0, stream>>>(enc, captions, emb, Wih,
                                                     bih, bhh, pre);
    fused_kernel<<<dim3(256), 256, 0, stream>>>(enc, captions, emb, Wih, bih,
                                                bhh, pre, Whh, Hall, flags,
                                                preCtr, Wfc, bfc, out,
                                                fused ? 1 : 0);
    if (!fused)
        out_kernel<<<dim3(16, 235), 256, 0, stream>>>(Hall, Wfc, bfc, out);
}